// Round 8
// baseline (258.637 us; speedup 1.0000x reference)
//
#include <hip/hip_runtime.h>

#define N_NEUR 512
#define B_SZ   16
#define T_STEPS 32
#define NIN    32
#define NOUT   16
#define CAPC   84   // chem nnz/row cap (mean 48.6, sd 6.63)
#define CAPG   52   // gj nnz/row cap   (mean 25.6, sd 4.93)
#define MC     42   // register slots per thread, chem (NO inflation: 128-reg wall)
#define MG     26
#define MCP    21
#define MGP    13
#define LOG2E  1.4426950408889634f

__device__ __forceinline__ float rcp_fast(float x) {
#if __has_builtin(__builtin_amdgcn_rcpf)
    return __builtin_amdgcn_rcpf(x);
#else
    return 1.0f / x;
#endif
}
__device__ __forceinline__ float exp2_fast(float x) {
#if __has_builtin(__builtin_amdgcn_exp2f)
    return __builtin_amdgcn_exp2f(x);
#else
    return exp2f(x);
#endif
}

// prep1: per row, softplus + mask + ballot-compact into per-row CSR.
__global__ __launch_bounds__(64) void prep1_kernel(
    const float* __restrict__ W,
    const float* __restrict__ mex,
    const float* __restrict__ min_,
    const float* __restrict__ mgj,
    int* __restrict__ key_arr, int* __restrict__ ccA, int* __restrict__ cgA,
    float* __restrict__ tmpCw, short* __restrict__ tmpCc,
    float* __restrict__ tmpGw, short* __restrict__ tmpGc)
{
    const int row  = blockIdx.x;
    const int lane = threadIdx.x;
    const unsigned long long below = (1ull << lane) - 1ull;
    int bc = 0, bg = 0;
    for (int c0 = 0; c0 < N_NEUR; c0 += 64) {
        const int col = c0 + lane;
        const int off = row * N_NEUR + col;
        const float w  = W[off];
        const float sp = fmaxf(w, 0.0f) + log1pf(__expf(-fabsf(w)));  // softplus
        const float dm = mex[off] - min_[off];                         // in {-1,0,1}
        bool a = (dm != 0.0f);
        unsigned long long m = __ballot(a);
        int idx = bc + __popcll(m & below);
        if (a && idx < CAPC) {
            tmpCw[row * CAPC + idx] = sp * dm;
            tmpCc[row * CAPC + idx] = (short)col;
        }
        bc += __popcll(m);

        const float g = mgj[off];
        bool ag = (g != 0.0f);
        m = __ballot(ag);
        idx = bg + __popcll(m & below);
        if (ag && idx < CAPG) {
            tmpGw[row * CAPG + idx] = sp * g;
            tmpGc[row * CAPG + idx] = (short)col;
        }
        bg += __popcll(m);
    }
    if (lane == 0) {
        int cc = min(bc, CAPC), cg = min(bg, CAPG);
        ccA[row] = cc; cgA[row] = cg; key_arr[row] = cc + cg;
    }
}

// rank: order[rank] = d, rank by (nnz asc, index) so waves hold similar counts.
__global__ __launch_bounds__(64) void rank_kernel(
    const int* __restrict__ key_arr, int* __restrict__ order)
{
    const int d    = blockIdx.x;
    const int lane = threadIdx.x;
    const int kd   = key_arr[d];
    int r = 0;
    for (int j = lane; j < N_NEUR; j += 64) {
        int kj = key_arr[j];
        r += (kj < kd) || (kj == kd && j < d);
    }
    #pragma unroll
    for (int i = 1; i < 64; i <<= 1) r += __shfl_xor(r, i);
    if (lane == 0) order[r] = d;
}

// greedy: one wave per main-kernel wave. PERMUTATION-ONLY bank scheduling
// (round-7's slot inflation broke the 128-reg wall -> spill). Per slot each
// lane proposes its first remaining entry; if that bank already has >=2
// commits this slot, tries its second; else force-commits the first (never
// leaves a hole beyond the lane's slack). Lanes with m < wave-max-m have
// (maxm - m) slots of slack to dodge congestion. Emits transposed layout +
// wave-max slot counts.
__global__ __launch_bounds__(64) void greedy_kernel(
    const int* __restrict__ order, const int* __restrict__ ccA, const int* __restrict__ cgA,
    const float* __restrict__ tmpCw, const short* __restrict__ tmpCc,
    const float* __restrict__ tmpGw, const short* __restrict__ tmpGc,
    float* __restrict__ wCt, unsigned* __restrict__ cpCt,
    float* __restrict__ wGt, unsigned* __restrict__ cpGt,
    int* __restrict__ nCarr, int* __restrict__ nGarr)
{
    __shared__ float wL[64 * MC];      // per-lane entry weights [L*M + j]
    __shared__ short cL[64 * MC];      // per-lane entry cols
    __shared__ short slotc[MC * 64];   // committed col per slot [k*64 + L]
    __shared__ int   propcnt[32];

    const int w = blockIdx.x;
    const int L = threadIdx.x;
    const int r = w * 32 + (L >> 1);
    const int h = L & 1;
    const int d = order[r];

    #pragma unroll
    for (int pass = 0; pass < 2; ++pass) {
        const int  cnt = pass ? cgA[d] : ccA[d];
        const int  CAP = pass ? CAPG : CAPC;
        const int  M   = pass ? MG   : MC;
        const int  MP  = pass ? MGP  : MCP;
        const float* tw = pass ? tmpGw : tmpCw;
        const short* tc = pass ? tmpGc : tmpCc;
        float*    wT = pass ? wGt  : wCt;
        unsigned* cT = pass ? cpGt : cpCt;

        const int m = (cnt + 1 - h) >> 1;          // this lane's entries
        for (int j = 0; j < m; ++j) {
            wL[L * M + j] = tw[d * CAP + 2 * j + h];
            cL[L * M + j] = tc[d * CAP + 2 * j + h];
        }
        int maxm = m;
        #pragma unroll
        for (int i = 1; i < 64; i <<= 1) maxm = max(maxm, __shfl_xor(maxm, i));

        unsigned long long rem = (1ull << m) - 1ull;   // m <= 42 < 64
        __syncthreads();
        for (int k = 0; k < maxm; ++k) {
            if (L < 32) propcnt[L] = 0;
            int myc = 0; float myw = 0.0f;
            if (rem) {
                int j0 = (int)__ffsll(rem) - 1;
                int c0 = cL[L * M + j0];
                bool force = (maxm - k) <= __popcll(rem);  // no slack left
                int p0 = atomicAdd(&propcnt[c0 & 31], 1);
                int take = j0;
                if (!force && p0 >= 2) {
                    unsigned long long rem2 = rem & (rem - 1);  // drop j0
                    if (rem2) {
                        int j1 = (int)__ffsll(rem2) - 1;
                        int c1 = cL[L * M + j1];
                        int p1 = atomicAdd(&propcnt[c1 & 31], 1);
                        if (p1 < 2) take = j1; else take = -1;  // skip slot
                    } else take = -1;
                }
                if (take >= 0) {
                    myc = cL[L * M + take]; myw = wL[L * M + take];
                    rem &= ~(1ull << take);
                }
            }
            slotc[k * 64 + L] = (short)myc;
            wT[(w * M + k) * 64 + L] = myw;
        }
        for (int k = maxm; k < M; ++k) {           // zero-fill tail
            slotc[k * 64 + L] = 0;
            wT[(w * M + k) * 64 + L] = 0.0f;
        }
        __syncthreads();
        for (int kp = 0; kp < MP; ++kp) {
            unsigned c0 = ((unsigned)(unsigned short)slotc[(2 * kp)     * 64 + L]) << 2;
            unsigned c1 = ((unsigned)(unsigned short)slotc[(2 * kp + 1) * 64 + L]) << 2;
            cT[(w * MP + kp) * 64 + L] = c0 | (c1 << 16);
        }
        if (L == 0) { if (pass) nGarr[w] = maxm; else nCarr[w] = maxm; }
        __syncthreads();
    }
}

#define CHEM_K(k, A) {                                                      \
    unsigned pk = cpC[(k) >> 1];                                            \
    unsigned off = ((k) & 1) ? (pk >> 16) : (pk & 0xffffu);                 \
    A = fmaf(wC[k], *(const float*)((const char*)ObP + off), A); }

#define CHEM_C4(a) { CHEM_K(a, accA) CHEM_K((a)+1, accB) CHEM_K((a)+2, accA) CHEM_K((a)+3, accB) }

#define GJ_K(k, A) {                                                        \
    unsigned pk = cpG[(k) >> 1];                                            \
    unsigned off = ((k) & 1) ? (pk >> 16) : (pk & 0xffffu);                 \
    float Os = *(const float*)((const char*)ObP + off);                     \
    float f = fmaf(20.0f * LOG2E, Os, cE);                                  \
    float tnh = 1.0f - 2.0f * rcp_fast(1.0f + exp2_fast(f));                \
    A = fmaf(wG[k] * Os, tnh, A); }

#define GJ_C4(a) { GJ_K(a, accA) GJ_K((a)+1, accB) GJ_K((a)+2, accA) GJ_K((a)+3, accB) }

// One full recurrence step with COMPILE-TIME buffer parity P: S[P]=O read,
// S[2+P]=E read, S[1-P]/S[3-P] written. Constant P folds the LDS base into
// the ds_read immediate (one less VALU op per gather).
#define STEP_BODY(P, tt) {                                                  \
    float ob_next = (inj && ((tt) + 1 < T_STEPS))                           \
                        ? obs_b[((tt) + 1) * NIN + d] : 0.0f;               \
    const float* ObP = &S[P][0];                                            \
    const float E_d = S[2 + (P)][d];                                        \
    float accA = 0.0f, accB = 0.0f;                                         \
    CHEM_C4(0)                                                              \
    if ( 4 < mCw) CHEM_C4(4)                                                \
    if ( 8 < mCw) CHEM_C4(8)                                                \
    if (12 < mCw) CHEM_C4(12)                                               \
    if (16 < mCw) CHEM_C4(16)                                               \
    if (20 < mCw) CHEM_C4(20)                                               \
    if (24 < mCw) CHEM_C4(24)                                               \
    if (28 < mCw) CHEM_C4(28)                                               \
    if (32 < mCw) CHEM_C4(32)                                               \
    if (36 < mCw) CHEM_C4(36)                                               \
    if (40 < mCw) { CHEM_K(40, accA) CHEM_K(41, accB) }                     \
    const float cE = -20.0f * LOG2E * E_d;                                  \
    GJ_C4(0)                                                                \
    if ( 4 < mGw) GJ_C4(4)                                                  \
    if ( 8 < mGw) GJ_C4(8)                                                  \
    if (12 < mGw) GJ_C4(12)                                                 \
    if (16 < mGw) GJ_C4(16)                                                 \
    if (20 < mGw) GJ_C4(20)                                                 \
    if (24 < mGw) { GJ_K(24, accA) GJ_K(25, accB) }                         \
    float acc = accA + accB;                                                \
    acc += __shfl_xor(acc, 1);                                              \
    float curr = fminf(fmaxf(E_d + acc, -10.0f), 10.0f);                    \
    float z = curr - thr_d;                                                 \
    float O_new = (z >= 0.0f) ? z : 0.01f * z;                              \
    float fg = rcp_fast(1.0f + exp2_fast(-10.0f * LOG2E * z));              \
    float dg = rcp_fast(1.0f + exp2_fast(-5.0f * LOG2E *                    \
                                         (fabsf(E_d - curr) - 0.01f)));     \
    float E_nf  = dg * curr + (1.0f - dg) * (E_d - dec_d);                  \
    float E_new = fg * O_new + (1.0f - fg) * E_nf;                          \
    if (h == 0) {                                                           \
        S[3 - (P)][d] = inj ? ob_next : E_new;                              \
        S[1 - (P)][d] = inj ? ob_next : O_new;                              \
        if (wr) outp[(tt) * NOUT] = E_new;                                  \
    }                                                                       \
    __syncthreads(); }

// main: one block per batch, 1024 threads = 2 per neuron (sorted by nnz).
// Lists in registers (greedy bank-permuted slots, 102 words — fits the
// 128-reg/thread wall at 4 waves/SIMD); one barrier per step; t-loop
// unrolled x2 for compile-time buffer parity.
__global__ __launch_bounds__(1024, 1) void recur_kernel(
    const float* __restrict__ obs,
    const float* __restrict__ thr,
    const float* __restrict__ dec,
    const int* __restrict__ order,
    const int* __restrict__ nCarr, const int* __restrict__ nGarr,
    const float* __restrict__ wCt, const unsigned* __restrict__ cpCt,
    const float* __restrict__ wGt, const unsigned* __restrict__ cpGt,
    float* __restrict__ out)
{
    __shared__ float S[4][N_NEUR];   // [0]=O_even [1]=O_odd [2]=E_even [3]=E_odd

    const int b    = blockIdx.x;
    const int tid  = threadIdx.x;
    const int h    = tid & 1;
    const int r    = tid >> 1;            // rank
    const int wv   = tid >> 6;
    const int lane = tid & 63;

    const int d = order[r];
    const float thr_d = thr[d];
    const float dec_d = dec[d];

    const int mCw = __builtin_amdgcn_readfirstlane(nCarr[wv]);
    const int mGw = __builtin_amdgcn_readfirstlane(nGarr[wv]);

    // register-resident bank-permuted lists (pad slots: w=0, col=0)
    float wC[MC]; unsigned cpC[MCP];
    float wG[MG]; unsigned cpG[MGP];
    #pragma unroll
    for (int k = 0; k < MC; ++k)  wC[k]  = wCt[(wv * MC + k) * 64 + lane];
    #pragma unroll
    for (int k = 0; k < MCP; ++k) cpC[k] = cpCt[(wv * MCP + k) * 64 + lane];
    #pragma unroll
    for (int k = 0; k < MG; ++k)  wG[k]  = wGt[(wv * MG + k) * 64 + lane];
    #pragma unroll
    for (int k = 0; k < MGP; ++k) cpG[k] = cpGt[(wv * MGP + k) * 64 + lane];

    const bool inj = (h == 0) && (d < NIN);
    const bool wr  = (h == 0) && (d >= NIN) && (d < NIN + NOUT);
    float* outp = out + (size_t)b * T_STEPS * NOUT + (d - NIN);
    const float* obs_b = obs + b * (T_STEPS * NIN);

    if (h == 0) {
        float v = (d < NIN) ? obs_b[d] : 0.0f;   // state 0 = zeros + obs_0
        S[0][d] = v;
        S[2][d] = v;
    }
    __syncthreads();

    for (int t = 0; t < T_STEPS; t += 2) {
        STEP_BODY(0, t)
        STEP_BODY(1, t + 1)
    }
}

extern "C" void kernel_launch(void* const* d_in, const int* in_sizes, int n_in,
                              void* d_out, int out_size, void* d_ws, size_t ws_size,
                              hipStream_t stream)
{
    const float* obs  = (const float*)d_in[0];
    const float* W    = (const float*)d_in[1];
    const float* thr  = (const float*)d_in[2];
    const float* dec  = (const float*)d_in[3];
    const float* mex  = (const float*)d_in[4];
    const float* min_ = (const float*)d_in[5];
    const float* mgj  = (const float*)d_in[6];
    float* out = (float*)d_out;

    char* ws = (char*)d_ws;
    int*   key_arr = (int*)(ws);                     // 2048
    int*   ccA     = (int*)(ws + 2048);              // 2048
    int*   cgA     = (int*)(ws + 4096);              // 2048
    int*   order   = (int*)(ws + 6144);              // 2048
    int*   nCarr   = (int*)(ws + 8192);              // 64
    int*   nGarr   = (int*)(ws + 8256);              // 64
    float* tmpCw   = (float*)(ws + 12288);           // 512*84*4 = 172032
    short* tmpCc   = (short*)(ws + 184320);          // 512*84*2 =  86016
    float* tmpGw   = (float*)(ws + 270336);          // 512*52*4 = 106496
    short* tmpGc   = (short*)(ws + 376832);          // 512*52*2 =  53248
    float* wCt     = (float*)(ws + 430080);          // 16*42*64*4 = 172032
    unsigned* cpCt = (unsigned*)(ws + 602112);       // 16*21*64*4 =  86016
    float* wGt     = (float*)(ws + 688128);          // 16*26*64*4 = 106496
    unsigned* cpGt = (unsigned*)(ws + 794624);       // 16*13*64*4 =  53248
    // total ws use: 847872 B

    prep1_kernel<<<N_NEUR, 64, 0, stream>>>(W, mex, min_, mgj,
                                            key_arr, ccA, cgA,
                                            tmpCw, tmpCc, tmpGw, tmpGc);
    rank_kernel<<<N_NEUR, 64, 0, stream>>>(key_arr, order);
    greedy_kernel<<<16, 64, 0, stream>>>(order, ccA, cgA,
                                         tmpCw, tmpCc, tmpGw, tmpGc,
                                         wCt, cpCt, wGt, cpGt, nCarr, nGarr);
    recur_kernel<<<B_SZ, 1024, 0, stream>>>(obs, thr, dec,
                                            order, nCarr, nGarr,
                                            wCt, cpCt, wGt, cpGt, out);
}

// Round 9
// 219.253 us; speedup vs baseline: 1.1796x; 1.1796x over previous
//
#include <hip/hip_runtime.h>

#define N_NEUR 512
#define B_SZ   16
#define T_STEPS 32
#define NIN    32
#define NOUT   16
#define CAPC   84   // chem nnz/row cap (mean 48.6, sd 6.63)
#define CAPG   52   // gj nnz/row cap   (mean 25.6, sd 4.93)
#define MC     42   // per-thread register slots (permutation only: 128-reg wall)
#define MG     26
#define MCP    21
#define MGP    13
#define LOG2E  1.4426950408889634f

__device__ __forceinline__ float rcp_fast(float x) {
#if __has_builtin(__builtin_amdgcn_rcpf)
    return __builtin_amdgcn_rcpf(x);
#else
    return 1.0f / x;
#endif
}
__device__ __forceinline__ float exp2_fast(float x) {
#if __has_builtin(__builtin_amdgcn_exp2f)
    return __builtin_amdgcn_exp2f(x);
#else
    return exp2f(x);
#endif
}

// prep1: per row, softplus + mask + ballot-compact into per-row CSR.
__global__ __launch_bounds__(64) void prep1_kernel(
    const float* __restrict__ W,
    const float* __restrict__ mex,
    const float* __restrict__ min_,
    const float* __restrict__ mgj,
    int* __restrict__ key_arr, int* __restrict__ ccA, int* __restrict__ cgA,
    float* __restrict__ tmpCw, short* __restrict__ tmpCc,
    float* __restrict__ tmpGw, short* __restrict__ tmpGc)
{
    const int row  = blockIdx.x;
    const int lane = threadIdx.x;
    const unsigned long long below = (1ull << lane) - 1ull;
    int bc = 0, bg = 0;
    for (int c0 = 0; c0 < N_NEUR; c0 += 64) {
        const int col = c0 + lane;
        const int off = row * N_NEUR + col;
        const float w  = W[off];
        const float sp = fmaxf(w, 0.0f) + log1pf(__expf(-fabsf(w)));  // softplus
        const float dm = mex[off] - min_[off];                         // in {-1,0,1}
        bool a = (dm != 0.0f);
        unsigned long long m = __ballot(a);
        int idx = bc + __popcll(m & below);
        if (a && idx < CAPC) {
            tmpCw[row * CAPC + idx] = sp * dm;
            tmpCc[row * CAPC + idx] = (short)col;
        }
        bc += __popcll(m);

        const float g = mgj[off];
        bool ag = (g != 0.0f);
        m = __ballot(ag);
        idx = bg + __popcll(m & below);
        if (ag && idx < CAPG) {
            tmpGw[row * CAPG + idx] = sp * g;
            tmpGc[row * CAPG + idx] = (short)col;
        }
        bg += __popcll(m);
    }
    if (lane == 0) {
        int cc = min(bc, CAPC), cg = min(bg, CAPG);
        ccA[row] = cc; cgA[row] = cg; key_arr[row] = cc + cg;
    }
}

// sched: one block per main-kernel wave (16 x 256). Fuses:
//  (a) RANK (counting sort, deterministic): rank(d) = prefix[key(d)] +
//      popcount(occupancy bits of same-key rows below d). Identical bijection
//      computed redundantly in every block -> no cross-block coordination.
//  (b) GREEDY bank permutation (wave 0 only, wave-lockstep): per slot,
//      4-round probe-verify-REPAIR (failed atomicAdd is atomicSub'd back so
//      counts stay truthful), force-commit only when slack runs out.
//      Permutation-only: per-thread slot count stays MC/MG (128-reg wall).
__global__ __launch_bounds__(256) void sched_kernel(
    const int* __restrict__ key_arr, const int* __restrict__ ccA, const int* __restrict__ cgA,
    const float* __restrict__ tmpCw, const short* __restrict__ tmpCc,
    const float* __restrict__ tmpGw, const short* __restrict__ tmpGc,
    int* __restrict__ order,
    float* __restrict__ wCt, unsigned* __restrict__ cpCt,
    float* __restrict__ wGt, unsigned* __restrict__ cpGt,
    int* __restrict__ nCarr, int* __restrict__ nGarr)
{
    __shared__ int      keyL[N_NEUR];
    __shared__ unsigned bm[144][16];     // per-key occupancy bitmask over d
    __shared__ int      hist[145];
    __shared__ short    dmap[32];
    __shared__ float    wL[64 * MC];     // greedy: per-lane entries
    __shared__ short    cL[64 * MC];
    __shared__ short    slotc[MC * 64];  // committed col per slot
    __shared__ int      propcnt[32];

    const int w   = blockIdx.x;
    const int tid = threadIdx.x;

    for (int i = tid; i < 144 * 16; i += 256) ((unsigned*)bm)[i] = 0u;
    if (tid < 145) hist[tid] = 0;
    __syncthreads();
    for (int j = tid; j < N_NEUR; j += 256) {
        int k = key_arr[j];
        keyL[j] = k;
        atomicAdd(&hist[k], 1);
        atomicOr(&bm[k][j >> 5], 1u << (j & 31));
    }
    __syncthreads();
    if (tid == 0) {
        int run = 0;
        for (int k = 0; k < 144; ++k) { int c = hist[k]; hist[k] = run; run += c; }
    }
    __syncthreads();
    for (int j = tid; j < N_NEUR; j += 256) {
        int k = keyL[j];
        int off = 0;
        for (int u = 0; u < (j >> 5); ++u) off += __popc(bm[k][u]);
        off += __popc(bm[k][j >> 5] & ((1u << (j & 31)) - 1u));
        int rank = hist[k] + off;
        if ((rank >> 5) == w) {
            dmap[rank & 31] = (short)j;
            order[rank] = j;          // each block writes its own 32 entries
        }
    }
    __syncthreads();

    if (tid < 64) {                   // greedy: single wave, lockstep
        const int L = tid;
        const int h = L & 1;
        const int d = dmap[L >> 1];

        for (int pass = 0; pass < 2; ++pass) {
            const int  cnt = pass ? cgA[d] : ccA[d];
            const int  CAP = pass ? CAPG : CAPC;
            const int  M   = pass ? MG   : MC;
            const int  MP  = pass ? MGP  : MCP;
            const float* tw = pass ? tmpGw : tmpCw;
            const short* tc = pass ? tmpGc : tmpCc;
            float*    wT = pass ? wGt  : wCt;
            unsigned* cT = pass ? cpGt : cpCt;

            const int m = (cnt + 1 - h) >> 1;      // this lane's entries
            for (int j = 0; j < m; ++j) {
                wL[L * M + j] = tw[d * CAP + 2 * j + h];
                cL[L * M + j] = tc[d * CAP + 2 * j + h];
            }
            int maxm = m;
            #pragma unroll
            for (int i = 1; i < 64; i <<= 1) maxm = max(maxm, __shfl_xor(maxm, i));

            unsigned long long rem = (1ull << m) - 1ull;   // m <= 42 < 64
            for (int k = 0; k < maxm; ++k) {
                if (L < 32) propcnt[L] = 0;
                int take = -1;
                if (rem) {
                    bool force = (maxm - k) <= __popcll(rem);  // slack gone
                    if (force) {
                        take = (int)__ffsll(rem) - 1;
                    } else {
                        unsigned long long rr = rem;
                        #pragma unroll
                        for (int round = 0; round < 4; ++round) {
                            if (take >= 0 || !rr) continue;
                            int j = (int)__ffsll(rr) - 1;
                            rr &= rr - 1;
                            int bk = cL[L * M + j] & 31;
                            if (propcnt[bk] < 2) {
                                int p = atomicAdd(&propcnt[bk], 1);
                                if (p < 2) take = j;
                                else atomicSub(&propcnt[bk], 1);  // repair
                            }
                        }
                    }
                }
                int myc = 0; float myw = 0.0f;
                if (take >= 0) {
                    myc = cL[L * M + take]; myw = wL[L * M + take];
                    rem &= ~(1ull << take);
                }
                slotc[k * 64 + L] = (short)myc;
                wT[(w * M + k) * 64 + L] = myw;
            }
            for (int k = maxm; k < M; ++k) {       // zero-fill tail
                slotc[k * 64 + L] = 0;
                wT[(w * M + k) * 64 + L] = 0.0f;
            }
            for (int kp = 0; kp < MP; ++kp) {
                unsigned c0 = ((unsigned)(unsigned short)slotc[(2 * kp)     * 64 + L]) << 2;
                unsigned c1 = ((unsigned)(unsigned short)slotc[(2 * kp + 1) * 64 + L]) << 2;
                cT[(w * MP + kp) * 64 + L] = c0 | (c1 << 16);
            }
            if (L == 0) { if (pass) nGarr[w] = maxm; else nCarr[w] = maxm; }
        }
    }
}

#define CHEM_K(k, A) {                                                      \
    unsigned pk = cpC[(k) >> 1];                                            \
    unsigned off = ((k) & 1) ? (pk >> 16) : (pk & 0xffffu);                 \
    A = fmaf(wC[k], *(const float*)((const char*)ObP + off), A); }

#define CHEM_C4(a) { CHEM_K(a, accA) CHEM_K((a)+1, accB) CHEM_K((a)+2, accA) CHEM_K((a)+3, accB) }

#define GJ_K(k, A) {                                                        \
    unsigned pk = cpG[(k) >> 1];                                            \
    unsigned off = ((k) & 1) ? (pk >> 16) : (pk & 0xffffu);                 \
    float Os = *(const float*)((const char*)ObP + off);                     \
    float f = fmaf(20.0f * LOG2E, Os, cE);                                  \
    float tnh = 1.0f - 2.0f * rcp_fast(1.0f + exp2_fast(f));                \
    A = fmaf(wG[k] * Os, tnh, A); }

#define GJ_C4(a) { GJ_K(a, accA) GJ_K((a)+1, accB) GJ_K((a)+2, accA) GJ_K((a)+3, accB) }

// main: EXACT round-6 structure (runtime buffer parity, single loop body —
// the x2-unrolled body re-spilled in round 8; this shape is the proven
// no-spill 128-reg fit). Lists = greedy bank-permuted slots; one barrier
// per step; wave-uniform chunk-4 guards from nCarr/nGarr.
__global__ __launch_bounds__(1024, 1) void recur_kernel(
    const float* __restrict__ obs,
    const float* __restrict__ thr,
    const float* __restrict__ dec,
    const int* __restrict__ order,
    const int* __restrict__ nCarr, const int* __restrict__ nGarr,
    const float* __restrict__ wCt, const unsigned* __restrict__ cpCt,
    const float* __restrict__ wGt, const unsigned* __restrict__ cpGt,
    float* __restrict__ out)
{
    __shared__ float Ob[2][N_NEUR];
    __shared__ float Eb[2][N_NEUR];

    const int b    = blockIdx.x;
    const int tid  = threadIdx.x;
    const int h    = tid & 1;
    const int r    = tid >> 1;            // rank
    const int wv   = tid >> 6;
    const int lane = tid & 63;

    const int d = order[r];
    const float thr_d = thr[d];
    const float dec_d = dec[d];

    const int mCw = __builtin_amdgcn_readfirstlane(nCarr[wv]);
    const int mGw = __builtin_amdgcn_readfirstlane(nGarr[wv]);

    // register-resident bank-permuted lists (pad slots: w=0, col=0)
    float wC[MC]; unsigned cpC[MCP];
    float wG[MG]; unsigned cpG[MGP];
    #pragma unroll
    for (int k = 0; k < MC; ++k)  wC[k]  = wCt[(wv * MC + k) * 64 + lane];
    #pragma unroll
    for (int k = 0; k < MCP; ++k) cpC[k] = cpCt[(wv * MCP + k) * 64 + lane];
    #pragma unroll
    for (int k = 0; k < MG; ++k)  wG[k]  = wGt[(wv * MG + k) * 64 + lane];
    #pragma unroll
    for (int k = 0; k < MGP; ++k) cpG[k] = cpGt[(wv * MGP + k) * 64 + lane];

    const bool inj = (h == 0) && (d < NIN);
    const bool wr  = (h == 0) && (d >= NIN) && (d < NIN + NOUT);
    float* outp = out + (size_t)b * T_STEPS * NOUT + (d - NIN);
    const float* obs_b = obs + b * (T_STEPS * NIN);

    if (h == 0) {
        float v = (d < NIN) ? obs_b[d] : 0.0f;   // state 0 = zeros + obs_0
        Ob[0][d] = v;
        Eb[0][d] = v;
    }
    int p = 0;
    __syncthreads();

    for (int t = 0; t < T_STEPS; ++t) {
        // prefetch obs_{t+1} (written into the next buffer at this step's end)
        float ob_next = (inj && (t + 1 < T_STEPS)) ? obs_b[(t + 1) * NIN + d] : 0.0f;

        const float* ObP = Ob[p];
        const float E_d = Eb[p][d];
        float accA = 0.0f, accB = 0.0f;
        // chem: chunks of 4, wave-uniform scalar guards, constant reg indices
        CHEM_C4(0)
        if ( 4 < mCw) CHEM_C4(4)
        if ( 8 < mCw) CHEM_C4(8)
        if (12 < mCw) CHEM_C4(12)
        if (16 < mCw) CHEM_C4(16)
        if (20 < mCw) CHEM_C4(20)
        if (24 < mCw) CHEM_C4(24)
        if (28 < mCw) CHEM_C4(28)
        if (32 < mCw) CHEM_C4(32)
        if (36 < mCw) CHEM_C4(36)
        if (40 < mCw) { CHEM_K(40, accA) CHEM_K(41, accB) }
        // gj
        const float cE = -20.0f * LOG2E * E_d;
        GJ_C4(0)
        if ( 4 < mGw) GJ_C4(4)
        if ( 8 < mGw) GJ_C4(8)
        if (12 < mGw) GJ_C4(12)
        if (16 < mGw) GJ_C4(16)
        if (20 < mGw) GJ_C4(20)
        if (24 < mGw) { GJ_K(24, accA) GJ_K(25, accB) }

        float acc = accA + accB;
        acc += __shfl_xor(acc, 1);

        // epilogue (both halves compute; h==0 writes)
        float curr = fminf(fmaxf(E_d + acc, -10.0f), 10.0f);
        float z = curr - thr_d;
        float O_new = (z >= 0.0f) ? z : 0.01f * z;
        float fg = rcp_fast(1.0f + exp2_fast(-10.0f * LOG2E * z));
        float dg = rcp_fast(1.0f + exp2_fast(-5.0f * LOG2E * (fabsf(E_d - curr) - 0.01f)));
        float E_nf  = dg * curr + (1.0f - dg) * (E_d - dec_d);
        float E_new = fg * O_new + (1.0f - fg) * E_nf;

        const int q = p ^ 1;
        if (h == 0) {
            Eb[q][d] = inj ? ob_next : E_new;
            Ob[q][d] = inj ? ob_next : O_new;
            if (wr) outp[t * NOUT] = E_new;
        }
        __syncthreads();
        p = q;
    }
}

extern "C" void kernel_launch(void* const* d_in, const int* in_sizes, int n_in,
                              void* d_out, int out_size, void* d_ws, size_t ws_size,
                              hipStream_t stream)
{
    const float* obs  = (const float*)d_in[0];
    const float* W    = (const float*)d_in[1];
    const float* thr  = (const float*)d_in[2];
    const float* dec  = (const float*)d_in[3];
    const float* mex  = (const float*)d_in[4];
    const float* min_ = (const float*)d_in[5];
    const float* mgj  = (const float*)d_in[6];
    float* out = (float*)d_out;

    char* ws = (char*)d_ws;
    int*   key_arr = (int*)(ws);                     // 2048
    int*   ccA     = (int*)(ws + 2048);              // 2048
    int*   cgA     = (int*)(ws + 4096);              // 2048
    int*   order   = (int*)(ws + 6144);              // 2048
    int*   nCarr   = (int*)(ws + 8192);              // 64
    int*   nGarr   = (int*)(ws + 8256);              // 64
    float* tmpCw   = (float*)(ws + 12288);           // 512*84*4 = 172032
    short* tmpCc   = (short*)(ws + 184320);          // 512*84*2 =  86016
    float* tmpGw   = (float*)(ws + 270336);          // 512*52*4 = 106496
    short* tmpGc   = (short*)(ws + 376832);          // 512*52*2 =  53248
    float* wCt     = (float*)(ws + 430080);          // 16*42*64*4 = 172032
    unsigned* cpCt = (unsigned*)(ws + 602112);       // 16*21*64*4 =  86016
    float* wGt     = (float*)(ws + 688128);          // 16*26*64*4 = 106496
    unsigned* cpGt = (unsigned*)(ws + 794624);       // 16*13*64*4 =  53248
    // total ws use: 847872 B

    prep1_kernel<<<N_NEUR, 64, 0, stream>>>(W, mex, min_, mgj,
                                            key_arr, ccA, cgA,
                                            tmpCw, tmpCc, tmpGw, tmpGc);
    sched_kernel<<<16, 256, 0, stream>>>(key_arr, ccA, cgA,
                                         tmpCw, tmpCc, tmpGw, tmpGc,
                                         order, wCt, cpCt, wGt, cpGt,
                                         nCarr, nGarr);
    recur_kernel<<<B_SZ, 1024, 0, stream>>>(obs, thr, dec,
                                            order, nCarr, nGarr,
                                            wCt, cpCt, wGt, cpGt, out);
}

// Round 10
// 212.940 us; speedup vs baseline: 1.2146x; 1.0296x over previous
//
#include <hip/hip_runtime.h>

#define N_NEUR 512
#define B_SZ   16
#define T_STEPS 32
#define NIN    32
#define NOUT   16
#define CAPC   84   // chem nnz/row cap (mean 48.6, sd 6.63)
#define CAPG   52   // gj nnz/row cap   (mean 25.6, sd 4.93)
#define MC     42   // per-thread register slots (permutation only: 128-reg wall)
#define MG     26
#define MCP    21
#define MGP    13
#define LOG2E  1.4426950408889634f

__device__ __forceinline__ float rcp_fast(float x) {
#if __has_builtin(__builtin_amdgcn_rcpf)
    return __builtin_amdgcn_rcpf(x);
#else
    return 1.0f / x;
#endif
}
__device__ __forceinline__ float exp2_fast(float x) {
#if __has_builtin(__builtin_amdgcn_exp2f)
    return __builtin_amdgcn_exp2f(x);
#else
    return exp2f(x);
#endif
}

// prep1: per row, softplus + mask + ballot-compact into per-row CSR.
__global__ __launch_bounds__(64) void prep1_kernel(
    const float* __restrict__ W,
    const float* __restrict__ mex,
    const float* __restrict__ min_,
    const float* __restrict__ mgj,
    int* __restrict__ key_arr, int* __restrict__ ccA, int* __restrict__ cgA,
    float* __restrict__ tmpCw, short* __restrict__ tmpCc,
    float* __restrict__ tmpGw, short* __restrict__ tmpGc)
{
    const int row  = blockIdx.x;
    const int lane = threadIdx.x;
    const unsigned long long below = (1ull << lane) - 1ull;
    int bc = 0, bg = 0;
    for (int c0 = 0; c0 < N_NEUR; c0 += 64) {
        const int col = c0 + lane;
        const int off = row * N_NEUR + col;
        const float w  = W[off];
        const float sp = fmaxf(w, 0.0f) + log1pf(__expf(-fabsf(w)));  // softplus
        const float dm = mex[off] - min_[off];                         // in {-1,0,1}
        bool a = (dm != 0.0f);
        unsigned long long m = __ballot(a);
        int idx = bc + __popcll(m & below);
        if (a && idx < CAPC) {
            tmpCw[row * CAPC + idx] = sp * dm;
            tmpCc[row * CAPC + idx] = (short)col;
        }
        bc += __popcll(m);

        const float g = mgj[off];
        bool ag = (g != 0.0f);
        m = __ballot(ag);
        idx = bg + __popcll(m & below);
        if (ag && idx < CAPG) {
            tmpGw[row * CAPG + idx] = sp * g;
            tmpGc[row * CAPG + idx] = (short)col;
        }
        bg += __popcll(m);
    }
    if (lane == 0) {
        int cc = min(bc, CAPC), cg = min(bg, CAPG);
        ccA[row] = cc; cgA[row] = cg; key_arr[row] = cc + cg;
    }
}

// sched: one block per main-kernel wave (16 x 256).
//  (a) RANK via counting sort (deterministic, redundant per block).
//  (b) GREEDY with TWO-COPY bank choice: O-state is stored twice in LDS
//      (copies 2048 B apart), so entry bank choices are {b, b^16}. 64
//      lanes/slot into 32 banks x 2 ways with 2 choices each is a cuckoo-
//      regime matching (round-9's single-choice system was at exact
//      capacity -> force-commits -> conflicts stuck at 1.04M). The chosen
//      copy is baked into the stored byte offset: col*4 + copy*2048.
//      Chem pass on wave 0, gj pass on wave 1 (parallel).
__global__ __launch_bounds__(256) void sched_kernel(
    const int* __restrict__ key_arr, const int* __restrict__ ccA, const int* __restrict__ cgA,
    const float* __restrict__ tmpCw, const short* __restrict__ tmpCc,
    const float* __restrict__ tmpGw, const short* __restrict__ tmpGc,
    int* __restrict__ order,
    float* __restrict__ wCt, unsigned* __restrict__ cpCt,
    float* __restrict__ wGt, unsigned* __restrict__ cpGt,
    int* __restrict__ nCarr, int* __restrict__ nGarr)
{
    __shared__ int      keyL[N_NEUR];
    __shared__ unsigned bm[144][16];     // per-key occupancy bitmask over d
    __shared__ int      hist[145];
    __shared__ short    dmap[32];
    __shared__ float    wLC[64 * MC]; __shared__ short cLC[64 * MC];
    __shared__ float    wLG[64 * MG]; __shared__ short cLG[64 * MG];
    __shared__ unsigned short slotC[MC * 64];
    __shared__ unsigned short slotG[MG * 64];
    __shared__ int      propC[32];
    __shared__ int      propG[32];

    const int w   = blockIdx.x;
    const int tid = threadIdx.x;

    for (int i = tid; i < 144 * 16; i += 256) ((unsigned*)bm)[i] = 0u;
    if (tid < 145) hist[tid] = 0;
    __syncthreads();
    for (int j = tid; j < N_NEUR; j += 256) {
        int k = key_arr[j];
        keyL[j] = k;
        atomicAdd(&hist[k], 1);
        atomicOr(&bm[k][j >> 5], 1u << (j & 31));
    }
    __syncthreads();
    if (tid == 0) {
        int run = 0;
        for (int k = 0; k < 144; ++k) { int c = hist[k]; hist[k] = run; run += c; }
    }
    __syncthreads();
    for (int j = tid; j < N_NEUR; j += 256) {
        int k = keyL[j];
        int off = 0;
        for (int u = 0; u < (j >> 5); ++u) off += __popc(bm[k][u]);
        off += __popc(bm[k][j >> 5] & ((1u << (j & 31)) - 1u));
        int rank = hist[k] + off;
        if ((rank >> 5) == w) {
            dmap[rank & 31] = (short)j;
            order[rank] = j;
        }
    }
    __syncthreads();

    const int wave = tid >> 6;
    const int L    = tid & 63;
    if (wave < 2) {                       // wave 0: chem, wave 1: gj
        const int isG = wave;
        const int h   = L & 1;
        const int d   = dmap[L >> 1];
        const int cnt = isG ? cgA[d] : ccA[d];
        const int CAP = isG ? CAPG : CAPC;
        const int M   = isG ? MG   : MC;
        const int MP  = isG ? MGP  : MCP;
        const float* tw = isG ? tmpGw : tmpCw;
        const short* tc = isG ? tmpGc : tmpCc;
        float* wL = isG ? wLG : wLC;
        short* cL = isG ? cLG : cLC;
        unsigned short* slotc = isG ? slotG : slotC;
        int* prop = isG ? propG : propC;
        float*    wT = isG ? wGt  : wCt;
        unsigned* cT = isG ? cpGt : cpCt;

        const int m = (cnt + 1 - h) >> 1;          // this lane's entries
        for (int j = 0; j < m; ++j) {
            wL[L * M + j] = tw[d * CAP + 2 * j + h];
            cL[L * M + j] = tc[d * CAP + 2 * j + h];
        }
        int maxm = m;
        #pragma unroll
        for (int i = 1; i < 64; i <<= 1) maxm = max(maxm, __shfl_xor(maxm, i));

        unsigned long long rem = (1ull << m) - 1ull;   // m <= 42 < 64
        for (int k = 0; k < maxm; ++k) {
            if (L < 32) prop[L] = 0;
            int take = -1, copy = 0;
            if (rem) {
                bool force = (maxm - k) <= __popcll(rem);  // slack gone
                if (force) {
                    take = (int)__ffsll(rem) - 1;
                    int bb = cL[L * M + take] & 31;
                    copy = (prop[bb] > prop[bb ^ 16]) ? 1 : 0;
                    atomicAdd(&prop[bb ^ (copy << 4)], 1);
                } else {
                    unsigned long long rr = rem;
                    #pragma unroll
                    for (int rd = 0; rd < 2; ++rd) {       // 2 entries
                        if (take >= 0 || !rr) continue;
                        int j = (int)__ffsll(rr) - 1;
                        rr &= rr - 1;
                        int bb = cL[L * M + j] & 31;
                        int c0 = (prop[bb] > prop[bb ^ 16]) ? 1 : 0;  // lesser-loaded first
                        #pragma unroll
                        for (int cc2 = 0; cc2 < 2; ++cc2) {  // 2 copies
                            if (take >= 0) continue;
                            int cy = (c0 ^ cc2) & 1;
                            int bk = bb ^ (cy << 4);
                            if (prop[bk] < 2) {
                                int p = atomicAdd(&prop[bk], 1);
                                if (p < 2) { take = j; copy = cy; }
                                else atomicSub(&prop[bk], 1);   // repair
                            }
                        }
                    }
                }
            }
            unsigned short val = 0; float myw = 0.0f;
            if (take >= 0) {
                int col = cL[L * M + take];
                val = (unsigned short)((col << 2) | (copy << 11));  // byte off + copy*2048
                myw = wL[L * M + take];
                rem &= ~(1ull << take);
            }
            slotc[k * 64 + L] = val;
            wT[(w * M + k) * 64 + L] = myw;
        }
        for (int k = maxm; k < M; ++k) {
            slotc[k * 64 + L] = 0;
            wT[(w * M + k) * 64 + L] = 0.0f;
        }
        for (int kp = 0; kp < MP; ++kp) {
            unsigned c0 = slotc[(2 * kp)     * 64 + L];
            unsigned c1 = slotc[(2 * kp + 1) * 64 + L];
            cT[(w * MP + kp) * 64 + L] = c0 | (c1 << 16);
        }
        if (L == 0) { if (isG) nGarr[w] = maxm; else nCarr[w] = maxm; }
    }
}

#define CHEM_K(k, A) {                                                      \
    unsigned pk = cpC[(k) >> 1];                                            \
    unsigned off = ((k) & 1) ? (pk >> 16) : (pk & 0xffffu);                 \
    A = fmaf(wC[k], *(const float*)((const char*)ObP + off), A); }

#define CHEM_C4(a) { CHEM_K(a, accA) CHEM_K((a)+1, accB) CHEM_K((a)+2, accA) CHEM_K((a)+3, accB) }

#define GJ_K(k, A) {                                                        \
    unsigned pk = cpG[(k) >> 1];                                            \
    unsigned off = ((k) & 1) ? (pk >> 16) : (pk & 0xffffu);                 \
    float Os = *(const float*)((const char*)ObP + off);                     \
    float f = fmaf(20.0f * LOG2E, Os, cE);                                  \
    float tnh = 1.0f - 2.0f * rcp_fast(1.0f + exp2_fast(f));                \
    A = fmaf(wG[k] * Os, tnh, A); }

#define GJ_C4(a) { GJ_K(a, accA) GJ_K((a)+1, accB) GJ_K((a)+2, accA) GJ_K((a)+3, accB) }

// main: round-6 proven no-spill structure; O-state duplicated (2 copies per
// parity, 2048 B apart) — h==1 lane writes copy 1 in the write phase (was
// idle); gather offsets already encode copy choice. One barrier per step.
__global__ __launch_bounds__(1024, 1) void recur_kernel(
    const float* __restrict__ obs,
    const float* __restrict__ thr,
    const float* __restrict__ dec,
    const int* __restrict__ order,
    const int* __restrict__ nCarr, const int* __restrict__ nGarr,
    const float* __restrict__ wCt, const unsigned* __restrict__ cpCt,
    const float* __restrict__ wGt, const unsigned* __restrict__ cpGt,
    float* __restrict__ out)
{
    __shared__ float SO[2][2][N_NEUR];   // [parity][copy][neuron]
    __shared__ float Eb[2][N_NEUR];

    const int b    = blockIdx.x;
    const int tid  = threadIdx.x;
    const int h    = tid & 1;
    const int r    = tid >> 1;            // rank
    const int wv   = tid >> 6;
    const int lane = tid & 63;

    const int d = order[r];
    const float thr_d = thr[d];
    const float dec_d = dec[d];

    const int mCw = __builtin_amdgcn_readfirstlane(nCarr[wv]);
    const int mGw = __builtin_amdgcn_readfirstlane(nGarr[wv]);

    // register-resident bank-scheduled lists (pad slots: w=0, off=0)
    float wC[MC]; unsigned cpC[MCP];
    float wG[MG]; unsigned cpG[MGP];
    #pragma unroll
    for (int k = 0; k < MC; ++k)  wC[k]  = wCt[(wv * MC + k) * 64 + lane];
    #pragma unroll
    for (int k = 0; k < MCP; ++k) cpC[k] = cpCt[(wv * MCP + k) * 64 + lane];
    #pragma unroll
    for (int k = 0; k < MG; ++k)  wG[k]  = wGt[(wv * MG + k) * 64 + lane];
    #pragma unroll
    for (int k = 0; k < MGP; ++k) cpG[k] = cpGt[(wv * MGP + k) * 64 + lane];

    const bool injB = (d < NIN);
    const bool wr   = (h == 0) && (d >= NIN) && (d < NIN + NOUT);
    float* outp = out + (size_t)b * T_STEPS * NOUT + (d - NIN);
    const float* obs_b = obs + b * (T_STEPS * NIN);

    {
        float v = injB ? obs_b[d] : 0.0f;    // state 0 = zeros + obs_0
        if (h == 0) { SO[0][0][d] = v; Eb[0][d] = v; }
        else        { SO[0][1][d] = v; }
    }
    int p = 0;
    __syncthreads();

    for (int t = 0; t < T_STEPS; ++t) {
        // prefetch obs_{t+1} (written into the next buffer at this step's end)
        float ob_next = (injB && (t + 1 < T_STEPS)) ? obs_b[(t + 1) * NIN + d] : 0.0f;

        const float* ObP = &SO[p][0][0];
        const float E_d = Eb[p][d];
        float accA = 0.0f, accB = 0.0f;
        // chem: chunks of 4, wave-uniform scalar guards, constant reg indices
        CHEM_C4(0)
        if ( 4 < mCw) CHEM_C4(4)
        if ( 8 < mCw) CHEM_C4(8)
        if (12 < mCw) CHEM_C4(12)
        if (16 < mCw) CHEM_C4(16)
        if (20 < mCw) CHEM_C4(20)
        if (24 < mCw) CHEM_C4(24)
        if (28 < mCw) CHEM_C4(28)
        if (32 < mCw) CHEM_C4(32)
        if (36 < mCw) CHEM_C4(36)
        if (40 < mCw) { CHEM_K(40, accA) CHEM_K(41, accB) }
        // gj
        const float cE = -20.0f * LOG2E * E_d;
        GJ_C4(0)
        if ( 4 < mGw) GJ_C4(4)
        if ( 8 < mGw) GJ_C4(8)
        if (12 < mGw) GJ_C4(12)
        if (16 < mGw) GJ_C4(16)
        if (20 < mGw) GJ_C4(20)
        if (24 < mGw) { GJ_K(24, accA) GJ_K(25, accB) }

        float acc = accA + accB;
        acc += __shfl_xor(acc, 1);

        // epilogue (both halves compute; each half writes one O copy)
        float curr = fminf(fmaxf(E_d + acc, -10.0f), 10.0f);
        float z = curr - thr_d;
        float O_new = (z >= 0.0f) ? z : 0.01f * z;
        float fg = rcp_fast(1.0f + exp2_fast(-10.0f * LOG2E * z));
        float dg = rcp_fast(1.0f + exp2_fast(-5.0f * LOG2E * (fabsf(E_d - curr) - 0.01f)));
        float E_nf  = dg * curr + (1.0f - dg) * (E_d - dec_d);
        float E_new = fg * O_new + (1.0f - fg) * E_nf;

        const int q = p ^ 1;
        float Ow = injB ? ob_next : O_new;
        if (h == 0) {
            Eb[q][d] = injB ? ob_next : E_new;
            SO[q][0][d] = Ow;
            if (wr) outp[t * NOUT] = E_new;
        } else {
            SO[q][1][d] = Ow;
        }
        __syncthreads();
        p = q;
    }
}

extern "C" void kernel_launch(void* const* d_in, const int* in_sizes, int n_in,
                              void* d_out, int out_size, void* d_ws, size_t ws_size,
                              hipStream_t stream)
{
    const float* obs  = (const float*)d_in[0];
    const float* W    = (const float*)d_in[1];
    const float* thr  = (const float*)d_in[2];
    const float* dec  = (const float*)d_in[3];
    const float* mex  = (const float*)d_in[4];
    const float* min_ = (const float*)d_in[5];
    const float* mgj  = (const float*)d_in[6];
    float* out = (float*)d_out;

    char* ws = (char*)d_ws;
    int*   key_arr = (int*)(ws);                     // 2048
    int*   ccA     = (int*)(ws + 2048);              // 2048
    int*   cgA     = (int*)(ws + 4096);              // 2048
    int*   order   = (int*)(ws + 6144);              // 2048
    int*   nCarr   = (int*)(ws + 8192);              // 64
    int*   nGarr   = (int*)(ws + 8256);              // 64
    float* tmpCw   = (float*)(ws + 12288);           // 512*84*4 = 172032
    short* tmpCc   = (short*)(ws + 184320);          // 512*84*2 =  86016
    float* tmpGw   = (float*)(ws + 270336);          // 512*52*4 = 106496
    short* tmpGc   = (short*)(ws + 376832);          // 512*52*2 =  53248
    float* wCt     = (float*)(ws + 430080);          // 16*42*64*4 = 172032
    unsigned* cpCt = (unsigned*)(ws + 602112);       // 16*21*64*4 =  86016
    float* wGt     = (float*)(ws + 688128);          // 16*26*64*4 = 106496
    unsigned* cpGt = (unsigned*)(ws + 794624);       // 16*13*64*4 =  53248
    // total ws use: 847872 B

    prep1_kernel<<<N_NEUR, 64, 0, stream>>>(W, mex, min_, mgj,
                                            key_arr, ccA, cgA,
                                            tmpCw, tmpCc, tmpGw, tmpGc);
    sched_kernel<<<16, 256, 0, stream>>>(key_arr, ccA, cgA,
                                         tmpCw, tmpCc, tmpGw, tmpGc,
                                         order, wCt, cpCt, wGt, cpGt,
                                         nCarr, nGarr);
    recur_kernel<<<B_SZ, 1024, 0, stream>>>(obs, thr, dec,
                                            order, nCarr, nGarr,
                                            wCt, cpCt, wGt, cpGt, out);
}

// Round 11
// 208.902 us; speedup vs baseline: 1.2381x; 1.0193x over previous
//
#include <hip/hip_runtime.h>

#define N_NEUR 512
#define B_SZ   16
#define T_STEPS 32
#define NIN    32
#define NOUT   16
#define CAPC   84   // chem nnz/row cap (mean 48.6, sd 6.63)
#define CAPG   52   // gj nnz/row cap   (mean 25.6, sd 4.93)
#define MC     42   // per-thread register slots (permutation only: 128-reg wall)
#define MG     26
#define MCP    21
#define MGP    13
#define CPY1   2112 // byte offset of O copy 1: 528 dwords; 528%32=16 -> bank b^16
#define LOG2E  1.4426950408889634f

__device__ __forceinline__ float rcp_fast(float x) {
#if __has_builtin(__builtin_amdgcn_rcpf)
    return __builtin_amdgcn_rcpf(x);
#else
    return 1.0f / x;
#endif
}
__device__ __forceinline__ float exp2_fast(float x) {
#if __has_builtin(__builtin_amdgcn_exp2f)
    return __builtin_amdgcn_exp2f(x);
#else
    return exp2f(x);
#endif
}

// prep1: per row, softplus + mask + ballot-compact into per-row CSR.
__global__ __launch_bounds__(64) void prep1_kernel(
    const float* __restrict__ W,
    const float* __restrict__ mex,
    const float* __restrict__ min_,
    const float* __restrict__ mgj,
    int* __restrict__ key_arr, int* __restrict__ ccA, int* __restrict__ cgA,
    float* __restrict__ tmpCw, short* __restrict__ tmpCc,
    float* __restrict__ tmpGw, short* __restrict__ tmpGc)
{
    const int row  = blockIdx.x;
    const int lane = threadIdx.x;
    const unsigned long long below = (1ull << lane) - 1ull;
    int bc = 0, bg = 0;
    for (int c0 = 0; c0 < N_NEUR; c0 += 64) {
        const int col = c0 + lane;
        const int off = row * N_NEUR + col;
        const float w  = W[off];
        const float sp = fmaxf(w, 0.0f) + log1pf(__expf(-fabsf(w)));  // softplus
        const float dm = mex[off] - min_[off];                         // in {-1,0,1}
        bool a = (dm != 0.0f);
        unsigned long long m = __ballot(a);
        int idx = bc + __popcll(m & below);
        if (a && idx < CAPC) {
            tmpCw[row * CAPC + idx] = sp * dm;
            tmpCc[row * CAPC + idx] = (short)col;
        }
        bc += __popcll(m);

        const float g = mgj[off];
        bool ag = (g != 0.0f);
        m = __ballot(ag);
        idx = bg + __popcll(m & below);
        if (ag && idx < CAPG) {
            tmpGw[row * CAPG + idx] = sp * g;
            tmpGc[row * CAPG + idx] = (short)col;
        }
        bg += __popcll(m);
    }
    if (lane == 0) {
        int cc = min(bc, CAPC), cg = min(bg, CAPG);
        ccA[row] = cc; cgA[row] = cg; key_arr[row] = cc + cg;
    }
}

// sched: one block per main-kernel wave (16 x 256).
//  (a) RANK via counting sort (deterministic, redundant per block).
//  (b) Coalesced CSR staging into LDS (round-9/10's per-lane serial global
//      walk was the uncoalesced ~40us overhead).
//  (c) GREEDY with TRUE two-copy bank choice. Round-10 bug: copy stride
//      2048 B = 512 dwords = bank-invariant (512%32==0) -> the two "choices"
//      aliased to one bank and the count model was corrupt (conflicts ROSE).
//      Copy 1 now sits at 2112 B (528 dwords, 528%32=16): real bank b^16.
__global__ __launch_bounds__(256) void sched_kernel(
    const int* __restrict__ key_arr, const int* __restrict__ ccA, const int* __restrict__ cgA,
    const float* __restrict__ tmpCw, const short* __restrict__ tmpCc,
    const float* __restrict__ tmpGw, const short* __restrict__ tmpGc,
    int* __restrict__ order,
    float* __restrict__ wCt, unsigned* __restrict__ cpCt,
    float* __restrict__ wGt, unsigned* __restrict__ cpGt,
    int* __restrict__ nCarr, int* __restrict__ nGarr)
{
    __shared__ int      keyL[N_NEUR];
    __shared__ unsigned bm[144][16];     // per-key occupancy bitmask over d
    __shared__ int      hist[145];
    __shared__ short    dmap[32];
    __shared__ float    wRowC[32 * CAPC]; __shared__ short cRowC[32 * CAPC];
    __shared__ float    wRowG[32 * CAPG]; __shared__ short cRowG[32 * CAPG];
    __shared__ unsigned short slotC[MC * 64];
    __shared__ unsigned short slotG[MG * 64];
    __shared__ int      propC[32];
    __shared__ int      propG[32];

    const int w   = blockIdx.x;
    const int tid = threadIdx.x;

    for (int i = tid; i < 144 * 16; i += 256) ((unsigned*)bm)[i] = 0u;
    if (tid < 145) hist[tid] = 0;
    __syncthreads();
    for (int j = tid; j < N_NEUR; j += 256) {
        int k = key_arr[j];
        keyL[j] = k;
        atomicAdd(&hist[k], 1);
        atomicOr(&bm[k][j >> 5], 1u << (j & 31));
    }
    __syncthreads();
    if (tid == 0) {
        int run = 0;
        for (int k = 0; k < 144; ++k) { int c = hist[k]; hist[k] = run; run += c; }
    }
    __syncthreads();
    for (int j = tid; j < N_NEUR; j += 256) {
        int k = keyL[j];
        int off = 0;
        for (int u = 0; u < (j >> 5); ++u) off += __popc(bm[k][u]);
        off += __popc(bm[k][j >> 5] & ((1u << (j & 31)) - 1u));
        int rank = hist[k] + off;
        if ((rank >> 5) == w) {
            dmap[rank & 31] = (short)j;
            order[rank] = j;
        }
    }
    __syncthreads();

    // coalesced CSR staging: consecutive tid -> consecutive entries of a row
    for (int i = tid; i < 32 * CAPC; i += 256) {
        int row = i / CAPC, s = i - row * CAPC;
        int d = dmap[row];
        wRowC[i] = tmpCw[d * CAPC + s];
        cRowC[i] = tmpCc[d * CAPC + s];
    }
    for (int i = tid; i < 32 * CAPG; i += 256) {
        int row = i / CAPG, s = i - row * CAPG;
        int d = dmap[row];
        wRowG[i] = tmpGw[d * CAPG + s];
        cRowG[i] = tmpGc[d * CAPG + s];
    }
    __syncthreads();

    const int wave = tid >> 6;
    const int L    = tid & 63;
    if (wave < 2) {                       // wave 0: chem, wave 1: gj
        const int isG = wave;
        const int h   = L & 1;
        const int row = L >> 1;
        const int d   = dmap[row];
        const int cnt = isG ? cgA[d] : ccA[d];
        const int CAP = isG ? CAPG : CAPC;
        const int M   = isG ? MG   : MC;
        const int MP  = isG ? MGP  : MCP;
        const float* wRow = isG ? wRowG : wRowC;
        const short* cRow = isG ? cRowG : cRowC;
        unsigned short* slotc = isG ? slotG : slotC;
        int* prop = isG ? propG : propC;
        float*    wT = isG ? wGt  : wCt;
        unsigned* cT = isG ? cpGt : cpCt;

        const int base = row * CAP + h;            // entry j -> cRow[base + 2j]
        const int m = (cnt + 1 - h) >> 1;          // this lane's entries
        int maxm = m;
        #pragma unroll
        for (int i = 1; i < 64; i <<= 1) maxm = max(maxm, __shfl_xor(maxm, i));

        unsigned long long rem = (1ull << m) - 1ull;   // m <= 42 < 64
        for (int k = 0; k < maxm; ++k) {
            if (L < 32) prop[L] = 0;
            int take = -1, copy = 0;
            if (rem) {
                bool force = (maxm - k) <= __popcll(rem);  // slack gone
                if (force) {
                    take = (int)__ffsll(rem) - 1;
                    int bb = cRow[base + 2 * take] & 31;
                    copy = (prop[bb] > prop[bb ^ 16]) ? 1 : 0;
                    atomicAdd(&prop[bb ^ (copy << 4)], 1);
                } else {
                    unsigned long long rr = rem;
                    #pragma unroll
                    for (int rd = 0; rd < 2; ++rd) {       // 2 candidate entries
                        if (take >= 0 || !rr) continue;
                        int j = (int)__ffsll(rr) - 1;
                        rr &= rr - 1;
                        int bb = cRow[base + 2 * j] & 31;
                        int c0 = (prop[bb] > prop[bb ^ 16]) ? 1 : 0;  // lesser first
                        #pragma unroll
                        for (int cc2 = 0; cc2 < 2; ++cc2) {  // 2 copies
                            if (take >= 0) continue;
                            int cy = (c0 ^ cc2) & 1;
                            int bk = bb ^ (cy << 4);
                            if (prop[bk] < 2) {
                                int p = atomicAdd(&prop[bk], 1);
                                if (p < 2) { take = j; copy = cy; }
                                else atomicSub(&prop[bk], 1);   // repair
                            }
                        }
                    }
                }
            }
            unsigned short val = 0; float myw = 0.0f;
            if (take >= 0) {
                int col = cRow[base + 2 * take];
                val = (unsigned short)((col << 2) + (copy ? CPY1 : 0));
                myw = wRow[base + 2 * take];
                rem &= ~(1ull << take);
            }
            slotc[k * 64 + L] = val;
            wT[(w * M + k) * 64 + L] = myw;
        }
        for (int k = maxm; k < M; ++k) {
            slotc[k * 64 + L] = 0;
            wT[(w * M + k) * 64 + L] = 0.0f;
        }
        for (int kp = 0; kp < MP; ++kp) {
            unsigned c0 = slotc[(2 * kp)     * 64 + L];
            unsigned c1 = slotc[(2 * kp + 1) * 64 + L];
            cT[(w * MP + kp) * 64 + L] = c0 | (c1 << 16);
        }
        if (L == 0) { if (isG) nGarr[w] = maxm; else nCarr[w] = maxm; }
    }
}

#define CHEM_K(k, A) {                                                      \
    unsigned pk = cpC[(k) >> 1];                                            \
    unsigned off = ((k) & 1) ? (pk >> 16) : (pk & 0xffffu);                 \
    A = fmaf(wC[k], *(const float*)((const char*)ObP + off), A); }

#define CHEM_C4(a) { CHEM_K(a, accA) CHEM_K((a)+1, accB) CHEM_K((a)+2, accA) CHEM_K((a)+3, accB) }

#define GJ_K(k, A) {                                                        \
    unsigned pk = cpG[(k) >> 1];                                            \
    unsigned off = ((k) & 1) ? (pk >> 16) : (pk & 0xffffu);                 \
    float Os = *(const float*)((const char*)ObP + off);                     \
    float f = fmaf(20.0f * LOG2E, Os, cE);                                  \
    float tnh = 1.0f - 2.0f * rcp_fast(1.0f + exp2_fast(f));                \
    A = fmaf(wG[k] * Os, tnh, A); }

#define GJ_C4(a) { GJ_K(a, accA) GJ_K((a)+1, accB) GJ_K((a)+2, accA) GJ_K((a)+3, accB) }

// main: round-6 proven no-spill structure; O-state duplicated with copy 1 at
// +2112 B (bank b^16 — the round-10 2048-B stride was bank-invariant). h==1
// lane writes copy 1 in the write phase. One barrier per step.
__global__ __launch_bounds__(1024, 1) void recur_kernel(
    const float* __restrict__ obs,
    const float* __restrict__ thr,
    const float* __restrict__ dec,
    const int* __restrict__ order,
    const int* __restrict__ nCarr, const int* __restrict__ nGarr,
    const float* __restrict__ wCt, const unsigned* __restrict__ cpCt,
    const float* __restrict__ wGt, const unsigned* __restrict__ cpGt,
    float* __restrict__ out)
{
    __shared__ float SO[2][1056];        // [parity][copy0: 0..511, copy1: 528..1039]
    __shared__ float Eb[2][N_NEUR];

    const int b    = blockIdx.x;
    const int tid  = threadIdx.x;
    const int h    = tid & 1;
    const int r    = tid >> 1;            // rank
    const int wv   = tid >> 6;
    const int lane = tid & 63;

    const int d = order[r];
    const float thr_d = thr[d];
    const float dec_d = dec[d];

    const int mCw = __builtin_amdgcn_readfirstlane(nCarr[wv]);
    const int mGw = __builtin_amdgcn_readfirstlane(nGarr[wv]);

    // register-resident bank-scheduled lists (pad slots: w=0, off=0)
    float wC[MC]; unsigned cpC[MCP];
    float wG[MG]; unsigned cpG[MGP];
    #pragma unroll
    for (int k = 0; k < MC; ++k)  wC[k]  = wCt[(wv * MC + k) * 64 + lane];
    #pragma unroll
    for (int k = 0; k < MCP; ++k) cpC[k] = cpCt[(wv * MCP + k) * 64 + lane];
    #pragma unroll
    for (int k = 0; k < MG; ++k)  wG[k]  = wGt[(wv * MG + k) * 64 + lane];
    #pragma unroll
    for (int k = 0; k < MGP; ++k) cpG[k] = cpGt[(wv * MGP + k) * 64 + lane];

    const bool injB = (d < NIN);
    const bool wr   = (h == 0) && (d >= NIN) && (d < NIN + NOUT);
    float* outp = out + (size_t)b * T_STEPS * NOUT + (d - NIN);
    const float* obs_b = obs + b * (T_STEPS * NIN);

    {
        float v = injB ? obs_b[d] : 0.0f;    // state 0 = zeros + obs_0
        if (h == 0) { SO[0][d] = v; Eb[0][d] = v; }
        else        { SO[0][528 + d] = v; }
    }
    int p = 0;
    __syncthreads();

    for (int t = 0; t < T_STEPS; ++t) {
        // prefetch obs_{t+1} (written into the next buffer at this step's end)
        float ob_next = (injB && (t + 1 < T_STEPS)) ? obs_b[(t + 1) * NIN + d] : 0.0f;

        const float* ObP = &SO[p][0];
        const float E_d = Eb[p][d];
        float accA = 0.0f, accB = 0.0f;
        // chem: chunks of 4, wave-uniform scalar guards, constant reg indices
        CHEM_C4(0)
        if ( 4 < mCw) CHEM_C4(4)
        if ( 8 < mCw) CHEM_C4(8)
        if (12 < mCw) CHEM_C4(12)
        if (16 < mCw) CHEM_C4(16)
        if (20 < mCw) CHEM_C4(20)
        if (24 < mCw) CHEM_C4(24)
        if (28 < mCw) CHEM_C4(28)
        if (32 < mCw) CHEM_C4(32)
        if (36 < mCw) CHEM_C4(36)
        if (40 < mCw) { CHEM_K(40, accA) CHEM_K(41, accB) }
        // gj
        const float cE = -20.0f * LOG2E * E_d;
        GJ_C4(0)
        if ( 4 < mGw) GJ_C4(4)
        if ( 8 < mGw) GJ_C4(8)
        if (12 < mGw) GJ_C4(12)
        if (16 < mGw) GJ_C4(16)
        if (20 < mGw) GJ_C4(20)
        if (24 < mGw) { GJ_K(24, accA) GJ_K(25, accB) }

        float acc = accA + accB;
        acc += __shfl_xor(acc, 1);

        // epilogue (both halves compute; each half writes one O copy)
        float curr = fminf(fmaxf(E_d + acc, -10.0f), 10.0f);
        float z = curr - thr_d;
        float O_new = (z >= 0.0f) ? z : 0.01f * z;
        float fg = rcp_fast(1.0f + exp2_fast(-10.0f * LOG2E * z));
        float dg = rcp_fast(1.0f + exp2_fast(-5.0f * LOG2E * (fabsf(E_d - curr) - 0.01f)));
        float E_nf  = dg * curr + (1.0f - dg) * (E_d - dec_d);
        float E_new = fg * O_new + (1.0f - fg) * E_nf;

        const int q = p ^ 1;
        float Ow = injB ? ob_next : O_new;
        if (h == 0) {
            Eb[q][d] = injB ? ob_next : E_new;
            SO[q][d] = Ow;
            if (wr) outp[t * NOUT] = E_new;
        } else {
            SO[q][528 + d] = Ow;
        }
        __syncthreads();
        p = q;
    }
}

extern "C" void kernel_launch(void* const* d_in, const int* in_sizes, int n_in,
                              void* d_out, int out_size, void* d_ws, size_t ws_size,
                              hipStream_t stream)
{
    const float* obs  = (const float*)d_in[0];
    const float* W    = (const float*)d_in[1];
    const float* thr  = (const float*)d_in[2];
    const float* dec  = (const float*)d_in[3];
    const float* mex  = (const float*)d_in[4];
    const float* min_ = (const float*)d_in[5];
    const float* mgj  = (const float*)d_in[6];
    float* out = (float*)d_out;

    char* ws = (char*)d_ws;
    int*   key_arr = (int*)(ws);                     // 2048
    int*   ccA     = (int*)(ws + 2048);              // 2048
    int*   cgA     = (int*)(ws + 4096);              // 2048
    int*   order   = (int*)(ws + 6144);              // 2048
    int*   nCarr   = (int*)(ws + 8192);              // 64
    int*   nGarr   = (int*)(ws + 8256);              // 64
    float* tmpCw   = (float*)(ws + 12288);           // 512*84*4 = 172032
    short* tmpCc   = (short*)(ws + 184320);          // 512*84*2 =  86016
    float* tmpGw   = (float*)(ws + 270336);          // 512*52*4 = 106496
    short* tmpGc   = (short*)(ws + 376832);          // 512*52*2 =  53248
    float* wCt     = (float*)(ws + 430080);          // 16*42*64*4 = 172032
    unsigned* cpCt = (unsigned*)(ws + 602112);       // 16*21*64*4 =  86016
    float* wGt     = (float*)(ws + 688128);          // 16*26*64*4 = 106496
    unsigned* cpGt = (unsigned*)(ws + 794624);       // 16*13*64*4 =  53248
    // total ws use: 847872 B

    prep1_kernel<<<N_NEUR, 64, 0, stream>>>(W, mex, min_, mgj,
                                            key_arr, ccA, cgA,
                                            tmpCw, tmpCc, tmpGw, tmpGc);
    sched_kernel<<<16, 256, 0, stream>>>(key_arr, ccA, cgA,
                                         tmpCw, tmpCc, tmpGw, tmpGc,
                                         order, wCt, cpCt, wGt, cpGt,
                                         nCarr, nGarr);
    recur_kernel<<<B_SZ, 1024, 0, stream>>>(obs, thr, dec,
                                            order, nCarr, nGarr,
                                            wCt, cpCt, wGt, cpGt, out);
}